// Round 10
// baseline (156.006 us; speedup 1.0000x reference)
//
#include <hip/hip_runtime.h>
#include <math.h>

#define B_ 4
#define N_ 2048
#define C_ 64
#define K_ 32
#define BN_ (B_ * N_)  // 8192

// ws float layout (all regions rewritten every launch before being read):
// [0]             WS_NLL   nll accumulator (zeroed by k_cluster block 0)
// [8]             WS_DONE  unsigned done-counter (zeroed by k_cluster block 0)
// [64, 8256)      MEANS    B*K*C, count-divide fused (k_cluster)
// [8320, 10368)   APART    1024 * {sum, cnt} (k_fused anchor blocks)
// [10432, 18624)  SX = emb.x+absc.x (k_cluster blocks 0-31)
// [18624, 26816)  SY = emb.y+absc.y (k_cluster blocks 0-31)
#define WS_NLL 0
#define WS_DONE 8
#define WS_MEANS 64
#define WS_APART 8320
#define WS_SX 10432
#define WS_SY 18624

// Lean pair step: mask values are {0,1}, so sum(m*(1-e)) = cnt - sum(m*e).
__device__ __forceinline__ void proc4(int4 m, float rx, float ry,
                                      float4 xs, float4 ys,
                                      float& S, int& cnt) {
  float dx, dy, d2;
  dx = rx - xs.x; dy = ry - ys.x; d2 = dx * dx + dy * dy;
  S += (float)m.x * __expf(d2 * -0.1f); cnt += m.x;
  dx = rx - xs.y; dy = ry - ys.y; d2 = dx * dx + dy * dy;
  S += (float)m.y * __expf(d2 * -0.1f); cnt += m.y;
  dx = rx - xs.z; dy = ry - ys.z; d2 = dx * dx + dy * dy;
  S += (float)m.z * __expf(d2 * -0.1f); cnt += m.z;
  dx = rx - xs.w; dy = ry - ys.w; d2 = dx * dx + dy * dy;
  S += (float)m.w * __expf(d2 * -0.1f); cnt += m.w;
}

// Kernel A: 128 blocks x 256 — cluster means via ballot-scan (R6 structure).
// Blocks 0-31 additionally write SX/SY (8192 elems); block 0 zeroes NLL/DONE.
// Runs first (short); produces everything kernel B needs.
__global__ __launch_bounds__(256) void k_cluster(
    const float* __restrict__ emb, const float* __restrict__ absc,
    const float* __restrict__ contr, const int* __restrict__ labels,
    float* __restrict__ ws) {
  __shared__ int lab[N_];          // 8 KB
  __shared__ float lsum[4][64];
  __shared__ float lcnt[4];
  int t = threadIdx.x, lane = t & 63, w = t >> 6;
  int bid = blockIdx.x;
  int b = bid >> 5, k = bid & 31;
  if (bid == 0 && t == 0) {
    ws[WS_NLL] = 0.0f;
    ((unsigned*)ws)[WS_DONE] = 0u;
  }
  int flat = bid * 256 + t;
  if (flat < BN_) {                // blocks 0-31: coordinate prep
    float2 ev = ((const float2*)emb)[flat];
    float2 av = ((const float2*)absc)[flat];
    ws[WS_SX + flat] = ev.x + av.x;
    ws[WS_SY + flat] = ev.y + av.y;
  }
  const int4* lab4 = (const int4*)(labels + b * N_);
  int4* l4 = (int4*)lab;
  l4[t] = lab4[t];
  l4[t + 256] = lab4[t + 256];
  __syncthreads();
  float acc = 0.0f, cnt = 0.0f;
  for (int g0 = w * 512; g0 < w * 512 + 512; g0 += 64) {
    unsigned long long mb = __ballot(lab[g0 + lane] == k);
    while (mb) {
      int bit = __ffsll(mb) - 1;
      mb &= mb - 1;
      int r = g0 + bit;
      float x = contr[(size_t)(b * N_ + r) * C_ + lane];
      float ss = x * x;
#pragma unroll
      for (int off = 32; off > 0; off >>= 1) ss += __shfl_xor(ss, off);
      acc += x * (1.0f / fmaxf(sqrtf(ss), 1e-12f));
      cnt += 1.0f;
    }
  }
  lsum[w][lane] = acc;
  if (lane == 0) lcnt[w] = cnt;
  __syncthreads();
  if (t < 64) {
    float s = lsum[0][t] + lsum[1][t] + lsum[2][t] + lsum[3][t];
    float c = lcnt[0] + lcnt[1] + lcnt[2] + lcnt[3];
    ws[WS_MEANS + (b * K_ + k) * C_ + t] = s / fmaxf(c, 1.0f);
  }
}

// Kernel B: 1280 blocks x 256, two concurrent roles (logits hides under the
// anchor mask-stream instead of serializing behind it):
//  blocks [0,256):    logits/softmax/nll. Block = 32 rows, 4 waves: wave w ->
//    colhalf ch=w&1 (cols ch*64..+64), rowhalf rh=w>>1 (rows rh*16..+16).
//    mk[16] register-resident per lane; rows via LDS wave-uniform b128
//    broadcasts; ILP=4 row groups (R8's no-spill structure); no
//    max-subtraction (|logit|<=1: cosine vs mean of unit vectors).
//  blocks [256,1280): streaming anchor (R9 structure) but coords read from
//    L2-hot ws SX/SY — no per-block LDS staging/barrier. Software-pipelined
//    4-group int4 stream, lean proc4, per-block partials.
// Every block bumps the done-counter; the 1280th reduces APART + writes out.
__global__ __launch_bounds__(256) void k_fused(
    const float* __restrict__ contr, const int* __restrict__ labels,
    const int* __restrict__ mask, float* __restrict__ ws,
    float* __restrict__ out) {
  __shared__ float lc[32 * C_];    // 8 KB (logits rows; unused by anchor)
  __shared__ float invr[32];
  __shared__ float lsv[2][32], ltl[32];
  __shared__ float red[8];
  __shared__ float fred[8];
  __shared__ int lastf;
  int t = threadIdx.x, lane = t & 63, w = t >> 6;
  int bid = blockIdx.x;
  if (bid < 256) {
    // ---------------- logits role ----------------
    int r0 = bid * 32;
    int ch = w & 1, rh = w >> 1;
    int j = ch * 64 + lane;
    const float4* mean4 = (const float4*)(ws + WS_MEANS);
    float4 mk[16];
#pragma unroll
    for (int q = 0; q < 16; ++q) mk[q] = mean4[j * 16 + q];
    const float4* c4 = (const float4*)(contr + (size_t)r0 * C_);
    float4* lc4 = (float4*)lc;
    lc4[t] = c4[t];
    lc4[t + 256] = c4[t + 256];
    __syncthreads();
    if (t < 32) {                  // 32 parallel per-row norms
      float ss = 0.0f;
#pragma unroll
      for (int q = 0; q < 16; ++q) {
        float4 v = lc4[t * 16 + q];
        ss += v.x * v.x + v.y * v.y + v.z * v.z + v.w * v.w;
      }
      invr[t] = 1.0f / fmaxf(sqrtf(ss), 1e-12f);
    }
    __syncthreads();
#pragma unroll 1
    for (int rg = 0; rg < 4; ++rg) {
      int rb = rh * 16 + rg * 4;
      const float4* cr = lc4 + rb * 16;
      float a0 = 0.0f, a1 = 0.0f, a2 = 0.0f, a3 = 0.0f;
#pragma unroll
      for (int q = 0; q < 16; ++q) {
        float4 m = mk[q];
        float4 c0 = cr[q], c1 = cr[16 + q], c2 = cr[32 + q], c3 = cr[48 + q];
        a0 += c0.x * m.x + c0.y * m.y + c0.z * m.z + c0.w * m.w;
        a1 += c1.x * m.x + c1.y * m.y + c1.z * m.z + c1.w * m.w;
        a2 += c2.x * m.x + c2.y * m.y + c2.z * m.z + c2.w * m.w;
        a3 += c3.x * m.x + c3.y * m.y + c3.z * m.z + c3.w * m.w;
      }
      float l0 = a0 * invr[rb + 0];
      float l1 = a1 * invr[rb + 1];
      float l2 = a2 * invr[rb + 2];
      float l3 = a3 * invr[rb + 3];
      float s0 = __expf(l0), s1 = __expf(l1), s2 = __expf(l2), s3 = __expf(l3);
#pragma unroll
      for (int off = 32; off > 0; off >>= 1) {
        s0 += __shfl_xor(s0, off);
        s1 += __shfl_xor(s1, off);
        s2 += __shfl_xor(s2, off);
        s3 += __shfl_xor(s3, off);
      }
      int tg0 = labels[r0 + rb + 0], tg1 = labels[r0 + rb + 1];
      int tg2 = labels[r0 + rb + 2], tg3 = labels[r0 + rb + 3];
      float t0 = __shfl(l0, tg0), t1 = __shfl(l1, tg1);
      float t2 = __shfl(l2, tg2), t3 = __shfl(l3, tg3);
      if (lane == 0) {
        lsv[ch][rb + 0] = s0; lsv[ch][rb + 1] = s1;
        lsv[ch][rb + 2] = s2; lsv[ch][rb + 3] = s3;
        if (ch == 0) { ltl[rb] = t0; ltl[rb + 1] = t1; ltl[rb + 2] = t2; ltl[rb + 3] = t3; }
      }
    }
    __syncthreads();
    if (t < 32) {
      float nll = __logf(lsv[0][t] + lsv[1][t]) - ltl[t];
#pragma unroll
      for (int off = 16; off > 0; off >>= 1) nll += __shfl_xor(nll, off);
      if (t == 0) atomicAdd(&ws[WS_NLL], nll);
    }
  } else {
    // ---------------- anchor role ----------------
    int aid = bid - 256;             // [0,1024)
    int b = aid >> 8;                // 256 blocks per batch
    int aid8 = aid & 255;
    const float* sxp = ws + WS_SX + b * N_;
    const float* syp = ws + WS_SY + b * N_;
    int cg = (aid8 & 1) * 256 + t;   // fixed float4 column group [0,512)
    float4 xs = ((const float4*)sxp)[cg];
    float4 ys = ((const float4*)syp)[cg];
    int rb0 = aid8 >> 1;             // block-uniform base row
    const int4* mp = (const int4*)mask + (size_t)b * (N_ * (size_t)N_ / 4)
                     + aid8 * 256 + t;
    int4 c0 = mp[0], c1 = mp[65536], c2 = mp[131072], c3 = mp[196608];
    float S = 0.0f;
    int cnt = 0;
#pragma unroll 1
    for (int g = 0; g < 3; ++g) {
      const int4* np = mp + (size_t)(g + 1) * 262144;
      int4 n0 = np[0], n1 = np[65536], n2 = np[131072], n3 = np[196608];
      int rr = rb0 + g * 512;
      proc4(c0, sxp[rr],       syp[rr],       xs, ys, S, cnt);
      proc4(c1, sxp[rr + 128], syp[rr + 128], xs, ys, S, cnt);
      proc4(c2, sxp[rr + 256], syp[rr + 256], xs, ys, S, cnt);
      proc4(c3, sxp[rr + 384], syp[rr + 384], xs, ys, S, cnt);
      c0 = n0; c1 = n1; c2 = n2; c3 = n3;
    }
    int rr = rb0 + 3 * 512;
    proc4(c0, sxp[rr],       syp[rr],       xs, ys, S, cnt);
    proc4(c1, sxp[rr + 128], syp[rr + 128], xs, ys, S, cnt);
    proc4(c2, sxp[rr + 256], syp[rr + 256], xs, ys, S, cnt);
    proc4(c3, sxp[rr + 384], syp[rr + 384], xs, ys, S, cnt);
    float cntf = (float)cnt;
    float acc = cntf - S;            // sum m*(1-e) = cnt - sum(m*e)
#pragma unroll
    for (int off = 32; off > 0; off >>= 1) {
      acc += __shfl_xor(acc, off);
      cntf += __shfl_xor(cntf, off);
    }
    if (lane == 0) { red[w * 2] = acc; red[w * 2 + 1] = cntf; }
    __syncthreads();
    if (t == 0) {
      ws[WS_APART + aid * 2 + 0] = red[0] + red[2] + red[4] + red[6];
      ws[WS_APART + aid * 2 + 1] = red[1] + red[3] + red[5] + red[7];
    }
  }
  // ---- last-block final combine (release/acquire via done-counter) ----
  __syncthreads();
  if (t == 0) {
    __threadfence();                 // release: my APART/NLL writes visible
    unsigned v = atomicAdd(&((unsigned*)ws)[WS_DONE], 1u);
    lastf = (v == 1279u);
  }
  __syncthreads();
  if (lastf) {
    __threadfence();                 // acquire: all blocks' writes visible
    float a = 0.0f, c = 0.0f;
    for (int i = t; i < 1024; i += 256) {
      a += ws[WS_APART + i * 2 + 0];
      c += ws[WS_APART + i * 2 + 1];
    }
#pragma unroll
    for (int off = 32; off > 0; off >>= 1) {
      a += __shfl_xor(a, off);
      c += __shfl_xor(c, off);
    }
    if (lane == 0) { fred[w * 2] = a; fred[w * 2 + 1] = c; }
    __syncthreads();
    if (t == 0) {
      float at = fred[0] + fred[2] + fred[4] + fred[6];
      float ct = fred[1] + fred[3] + fred[5] + fred[7];
      out[0] = at / ct + 10.0f * ws[WS_NLL] * (1.0f / (float)BN_);
    }
  }
}

extern "C" void kernel_launch(void* const* d_in, const int* in_sizes, int n_in,
                              void* d_out, int out_size, void* d_ws, size_t ws_size,
                              hipStream_t stream) {
  const float* emb    = (const float*)d_in[0];
  const float* contr  = (const float*)d_in[1];
  const float* absc   = (const float*)d_in[2];
  const int*   mask   = (const int*)d_in[3];
  const int*   labels = (const int*)d_in[4];
  float* ws  = (float*)d_ws;
  float* out = (float*)d_out;

  k_cluster<<<B_ * K_, 256, 0, stream>>>(emb, absc, contr, labels, ws);
  k_fused<<<256 + 1024, 256, 0, stream>>>(contr, labels, mask, ws, out);
}